// Round 1
// 4696.654 us; speedup vs baseline: 1.0093x; 1.0093x over previous
//
#include <hip/hip_runtime.h>
#include <hip/hip_fp16.h>
#include <stdint.h>
#include <stddef.h>

// DRNN (dilated 3-layer LSTM), B=128, T=1024, F=128, H=256, dil=[1,2,4].
//  - Input GEMMs hoisted out of recurrence (f16 MFMA 16x16x32), G in 67MB chunks.
//  - Recurrence: batch element -> PAIR of WGs (512 gate cols each), W_hh in VGPRs,
//    h broadcast via v_readlane + v_dot2_f32_f16.
//  - R3: single-word relaxed agent atomics {tag32|f16x2}, parity double-buffered.
//  - R4 changes:
//      * pair = (blk, blk+128) instead of (2b,2b+1): same XCD under round-robin
//        block->XCD dispatch (128 % 8 == 0) -> shorter exchange RTT.
//      * 4-way split accumulators: breaks the 128-deep dependent fdot2 chain.
//      * lane-redundant LSTM cell (all 512 threads compute dims 2*lane,2*lane+1):
//        hp_own produced in-register; second __syncthreads and hbufw LDS removed;
//        gbuf parity double-buffered (one barrier/step, anti-dep safe).
//      * stores spread across waves: publish=wave0, Hout=wave1, y-bcast=waves2-5.

typedef _Float16 f16;
typedef _Float16 v2h __attribute__((ext_vector_type(2)));
typedef _Float16 v8h __attribute__((ext_vector_type(8)));
typedef __fp16 h2_raw __attribute__((ext_vector_type(2)));
typedef __fp16 h8_raw __attribute__((ext_vector_type(8)));
typedef float v4f __attribute__((ext_vector_type(4)));
typedef unsigned long long u64;

#define DEVINL static __device__ __forceinline__

DEVINL float sigm(float x) { return 1.0f / (1.0f + __expf(-x)); }
DEVINL float tanh_(float x) {
  x = fminf(fmaxf(x, -15.0f), 15.0f);
  float e = __expf(-2.0f * x);
  return (1.0f - e) / (1.0f + e);
}
DEVINL v2h pack2(float a, float b) {
  return __builtin_bit_cast(v2h, __builtin_amdgcn_cvt_pkrtz(a, b));
}
DEVINL v2h bcast_pair(v2h v, int l) {
  int i = __builtin_bit_cast(int, v);
  i = __builtin_amdgcn_readlane(i, l);
  return __builtin_bit_cast(v2h, i);
}
DEVINL float fdot2(v2h a, v2h b, float c) {
  return __builtin_amdgcn_fdot2(__builtin_bit_cast(h2_raw, a),
                                __builtin_bit_cast(h2_raw, b), c, false);
}
DEVINL v4f mfma_16x16x32(v8h a, v8h b, v4f c) {
  return __builtin_amdgcn_mfma_f32_16x16x32_f16(__builtin_bit_cast(h8_raw, a),
                                                __builtin_bit_cast(h8_raw, b), c,
                                                0, 0, 0);
}

// ---------------- prep ----------------

__global__ void k_cvt_x(const float2* __restrict__ src, v2h* __restrict__ dst, int n2) {
  int i = blockIdx.x * blockDim.x + threadIdx.x;
  int st = gridDim.x * blockDim.x;
  for (; i < n2; i += st) {
    float2 v = src[i];
    dst[i] = pack2(v.x, v.y);
  }
}

__global__ void k_prep_w(const float* __restrict__ wih0, const float* __restrict__ whh0,
                         const float* __restrict__ wih1, const float* __restrict__ whh1,
                         const float* __restrict__ wih2, const float* __restrict__ whh2,
                         const float* __restrict__ bi0, const float* __restrict__ bh0,
                         const float* __restrict__ bi1, const float* __restrict__ bh1,
                         const float* __restrict__ bi2, const float* __restrict__ bh2,
                         f16* wih0f, f16* whh0f, f16* wih1f, f16* whh1f,
                         f16* wih2f, f16* whh2f,
                         float* bias0, float* bias1, float* bias2) {
  int i = blockIdx.x * blockDim.x + threadIdx.x;  // grid covers 262144
  if (i < 131072) wih0f[i] = (f16)wih0[i];
  whh0f[i] = (f16)whh0[i];
  wih1f[i] = (f16)wih1[i];
  whh1f[i] = (f16)whh1[i];
  wih2f[i] = (f16)wih2[i];
  whh2f[i] = (f16)whh2[i];
  if (i < 1024) {
    bias0[i] = bi0[i] + bh0[i];
    bias1[i] = bi1[i] + bh1[i];
    bias2[i] = bi2[i] + bh2[i];
  }
}

// ---------------- input GEMM (not a bottleneck; unchanged) ----------------

template <int K>
__launch_bounds__(256)
__global__ void k_gemm(const f16* __restrict__ A, int Tb, int t0,
                       const f16* __restrict__ W, const float* __restrict__ bias,
                       f16* __restrict__ G) {
  constexpr int LDK = K + 8;
  __shared__ f16 As[64 * LDK];
  int b = blockIdx.x >> 2, tb = blockIdx.x & 3;
  const f16* Ablk = A + ((size_t)b * Tb + t0 + tb * 64) * K;
  int tid = threadIdx.x;

  constexpr int NV = 64 * K / 8;
  const uint4* src = (const uint4*)Ablk;
  for (int i = tid; i < NV; i += 256) {
    int e = i * 8;
    int r = e / K, c0 = e % K;
    *(uint4*)&As[r * LDK + c0] = src[i];
  }
  __syncthreads();

  int wave = tid >> 6, lane = tid & 63;
  int lm = lane & 15, lk = (lane >> 4) * 8;

  v8h af[K / 32];
#pragma unroll
  for (int kc = 0; kc < K / 32; ++kc)
    af[kc] = *(const v8h*)&As[(wave * 16 + lm) * LDK + kc * 32 + lk];

  size_t grow0 = (size_t)b * 256 + tb * 64 + wave * 16;
  for (int nt = 0; nt < 64; ++nt) {
    v4f acc = {0.0f, 0.0f, 0.0f, 0.0f};
    const f16* Wrow = W + (size_t)(nt * 16 + lm) * K + lk;
#pragma unroll
    for (int kc = 0; kc < K / 32; ++kc) {
      v8h bf = *(const v8h*)(Wrow + kc * 32);
      acc = mfma_16x16x32(af[kc], bf, acc);
    }
    float bv = bias[nt * 16 + lm];
#pragma unroll
    for (int r = 0; r < 4; ++r) {
      int m = (lane >> 4) * 4 + r;
      G[(grow0 + m) * 1024 + nt * 16 + lm] = (f16)(acc[r] + bv);
    }
  }
}

// ---------------- recurrence ----------------
// grid 256 x 512 threads. b=blk&127, half=blk>>7 (pair (i,i+128): same XCD).
// Thread owns gate col g*256 + half*128 + j for the dot phase; every lane
// redundantly runs the cell for h-dims (2*lane, 2*lane+1) so hp_own is
// in-register -> one barrier/step (gbuf parity double-buffered).
// Exchange: hxw[(b*2+half)*128 + parity*64 + lane] = {tag=t+1 | f16x2 h},
// relaxed agent atomics, parity = t&1 (overwrite-while-reading impossible).

template <int LAYER>
__launch_bounds__(512, 2)
__global__ void k_rec(const f16* __restrict__ G,   // chunk [128][256][1024] f16
                      const f16* __restrict__ Whh, // [1024][256] f16
                      int t0, int steps,
                      f16* __restrict__ Hout, float* __restrict__ y,
                      float* __restrict__ hstate, float* __restrict__ cstate,
                      u64* hxw) {
  int blk = blockIdx.x;
  int b = blk & 127, half = blk >> 7;   // pair (i, i+128) -> same XCD
  int tid = threadIdx.x;
  int lane = tid & 63;
  int wv = tid >> 6;
  int g = tid >> 7, j = tid & 127;
  int col = g * 256 + half * 128 + j;

  __shared__ float gbuf[2][512];

  // W_hh row for this col -> registers. w0: own-half k, w1: partner-half k.
  v2h w0[64], w1[64];
  {
    const v8h* wown = (const v8h*)(Whh + (size_t)col * 256 + half * 128);
    const v8h* woth = (const v8h*)(Whh + (size_t)col * 256 + (1 - half) * 128);
#pragma unroll
    for (int i = 0; i < 16; ++i) {
      v8h qa = wown[i], qb = woth[i];
#pragma unroll
      for (int p = 0; p < 4; ++p) {
        v2h ta, tb;
        ta[0] = qa[2 * p]; ta[1] = qa[2 * p + 1];
        tb[0] = qb[2 * p]; tb[1] = qb[2 * p + 1];
        w0[i * 4 + p] = ta;
        w1[i * 4 + p] = tb;
      }
    }
  }

  u64* myw = hxw + (size_t)(b * 2 + half) * 128;
  const u64* pw = hxw + (size_t)(b * 2 + (1 - half)) * 128;

  float c0 = 0.0f, c1 = 0.0f, h0 = 0.0f, h1 = 0.0f;
  v2h hp_own = pack2(0.0f, 0.0f), hp_oth = pack2(0.0f, 0.0f);

  if (t0 > 0) {  // restore own-half state (partner half arrives via word poll)
    int sbase = b * 256 + half * 128 + 2 * lane;
    float2 a = *(const float2*)&hstate[sbase];
    float2 cc = *(const float2*)&cstate[sbase];
    hp_own = pack2(a.x, a.y);
    h0 = a.x; h1 = a.y; c0 = cc.x; c1 = cc.y;
  }

  const f16* Gp = G + (size_t)b * 256 * 1024 + col;
  float gcur = (float)Gp[0];

  for (int s = 0; s < steps; ++s) {
    int t = t0 + s;

    // issue partner poll + next-G prefetch early; own-half dots hide the latency
    const u64* pwp = pw + (((t - 1) & 1) << 6) + lane;
    u64 wp = 0;
    if (t > 0)
      wp = __hip_atomic_load(pwp, __ATOMIC_RELAXED, __HIP_MEMORY_SCOPE_AGENT);
    float gnext = (s + 1 < steps) ? (float)Gp[(size_t)(s + 1) << 10] : 0.0f;

    // 4-way split accumulators: 4 independent dot chains instead of one
    float a0 = gcur, a1 = 0.0f, a2 = 0.0f, a3 = 0.0f;
#pragma unroll
    for (int kk = 0; kk < 64; kk += 4) {
      a0 = fdot2(w0[kk + 0], bcast_pair(hp_own, kk + 0), a0);
      a1 = fdot2(w0[kk + 1], bcast_pair(hp_own, kk + 1), a1);
      a2 = fdot2(w0[kk + 2], bcast_pair(hp_own, kk + 2), a2);
      a3 = fdot2(w0[kk + 3], bcast_pair(hp_own, kk + 3), a3);
    }

    if (t > 0) {  // tag+payload in one atomic word: no fence needed
      while ((int)(wp >> 32) < t)
        wp = __hip_atomic_load(pwp, __ATOMIC_RELAXED, __HIP_MEMORY_SCOPE_AGENT);
      hp_oth = __builtin_bit_cast(v2h, (uint32_t)wp);
    }

#pragma unroll
    for (int kk = 0; kk < 64; kk += 4) {
      a0 = fdot2(w1[kk + 0], bcast_pair(hp_oth, kk + 0), a0);
      a1 = fdot2(w1[kk + 1], bcast_pair(hp_oth, kk + 1), a1);
      a2 = fdot2(w1[kk + 2], bcast_pair(hp_oth, kk + 2), a2);
      a3 = fdot2(w1[kk + 3], bcast_pair(hp_oth, kk + 3), a3);
    }

    gbuf[t & 1][tid] = (a0 + a1) + (a2 + a3);
    __syncthreads();  // the ONLY barrier per step

    // lane-redundant LSTM cell for dims (2*lane, 2*lane+1); gate order i,f,g,o
    const float* gb = gbuf[t & 1];
    float2 gi = *(const float2*)&gb[2 * lane];
    float2 gf = *(const float2*)&gb[2 * lane + 128];
    float2 gg = *(const float2*)&gb[2 * lane + 256];
    float2 go = *(const float2*)&gb[2 * lane + 384];
    c0 = sigm(gf.x) * c0 + sigm(gi.x) * tanh_(gg.x);
    c1 = sigm(gf.y) * c1 + sigm(gi.y) * tanh_(gg.y);
    h0 = sigm(go.x) * tanh_(c0);
    h1 = sigm(go.y) * tanh_(c1);
    hp_own = pack2(h0, h1);  // in-register: no LDS round-trip, no 2nd barrier

    if (wv == 0) {  // publish FIRST (shortest cross-WG path)
      uint32_t pk = __builtin_bit_cast(uint32_t, hp_own);
      u64 word = ((u64)(uint32_t)(t + 1) << 32) | (u64)pk;
      __hip_atomic_store(&myw[((t & 1) << 6) + lane], word,
                         __ATOMIC_RELAXED, __HIP_MEMORY_SCOPE_AGENT);
    }
    if (LAYER == 0) {
      if (wv == 1 && (t & 1) == 0) {
        v2h hr; hr[0] = (f16)h0; hr[1] = (f16)h1;  // RNE, matches R3 Hout path
        *(uint32_t*)&Hout[((size_t)b * 512 + (t >> 1)) * 256 + half * 128 + 2 * lane] =
            __builtin_bit_cast(uint32_t, hr);
      }
    } else if (LAYER == 1) {
      if (wv == 1 && (t & 1) == 0) {
        v2h hr; hr[0] = (f16)h0; hr[1] = (f16)h1;
        *(uint32_t*)&Hout[((size_t)b * 256 + (t >> 1)) * 256 + half * 128 + 2 * lane] =
            __builtin_bit_cast(uint32_t, hr);
      }
    } else {
      if (wv >= 2 && wv < 6) {  // 4x time-broadcast spread over waves 2..5
        size_t base = ((size_t)b * 1024 + (size_t)t * 4 + (wv - 2)) * 256 +
                      half * 128 + 2 * lane;
        float2 hv; hv.x = h0; hv.y = h1;
        *(float2*)&y[base] = hv;
      }
    }
    gcur = gnext;
  }

  if (wv == 0) {  // chunk state (own half; partner WG writes its half)
    int sbase = b * 256 + half * 128 + 2 * lane;
    float2 hv; hv.x = h0; hv.y = h1;
    float2 cv; cv.x = c0; cv.y = c1;
    *(float2*)&hstate[sbase] = hv;
    *(float2*)&cstate[sbase] = cv;
  }
}

// ---------------- orchestration ----------------

extern "C" void kernel_launch(void* const* d_in, const int* in_sizes, int n_in,
                              void* d_out, int out_size, void* d_ws, size_t ws_size,
                              hipStream_t stream) {
  const float* x = (const float*)d_in[0];
  const float* wih[3] = {(const float*)d_in[1], (const float*)d_in[5], (const float*)d_in[9]};
  const float* whh[3] = {(const float*)d_in[2], (const float*)d_in[6], (const float*)d_in[10]};
  const float* bi[3] = {(const float*)d_in[3], (const float*)d_in[7], (const float*)d_in[11]};
  const float* bh[3] = {(const float*)d_in[4], (const float*)d_in[8], (const float*)d_in[12]};
  float* y = (float*)d_out;

  // workspace layout (~155 MB total)
  char* p = (char*)d_ws;
  f16* Xf = (f16*)p;        p += (size_t)16777216 * 2;        // 33.5 MB
  f16* Wih0f = (f16*)p;     p += (size_t)131072 * 2;
  f16* Whh0f = (f16*)p;     p += (size_t)262144 * 2;
  f16* Wih1f = (f16*)p;     p += (size_t)262144 * 2;
  f16* Whh1f = (f16*)p;     p += (size_t)262144 * 2;
  f16* Wih2f = (f16*)p;     p += (size_t)262144 * 2;
  f16* Whh2f = (f16*)p;     p += (size_t)262144 * 2;
  float* bias0 = (float*)p; p += 4096;
  float* bias1 = (float*)p; p += 4096;
  float* bias2 = (float*)p; p += 4096;
  f16* Gbuf = (f16*)p;      p += (size_t)32768 * 1024 * 2;    // 67 MB chunk
  f16* H0e = (f16*)p;       p += (size_t)128 * 512 * 256 * 2; // 33.5 MB
  f16* H1q = (f16*)p;       p += (size_t)128 * 256 * 256 * 2; // 16.8 MB
  float* hstate = (float*)p; p += (size_t)128 * 256 * 4;
  float* cstate = (float*)p; p += (size_t)128 * 256 * 4;
  u64* hxw0 = (u64*)p;      p += (size_t)128 * 2 * 128 * 8;   // 256 KB, tagged words
  u64* hxw1 = (u64*)p;      p += (size_t)128 * 2 * 128 * 8;
  u64* hxw2 = (u64*)p;      p += (size_t)128 * 2 * 128 * 8;

  // prep
  k_cvt_x<<<4096, 256, 0, stream>>>((const float2*)x, (v2h*)Xf, 8388608);
  k_prep_w<<<1024, 256, 0, stream>>>(wih[0], whh[0], wih[1], whh[1], wih[2], whh[2],
                                     bi[0], bh[0], bi[1], bh[1], bi[2], bh[2],
                                     Wih0f, Whh0f, Wih1f, Whh1f, Wih2f, Whh2f,
                                     bias0, bias1, bias2);

  // layer 0: 4 chunks of 256 steps
  for (int c = 0; c < 4; ++c) {
    k_gemm<128><<<512, 256, 0, stream>>>(Xf, 1024, c * 256, Wih0f, bias0, Gbuf);
    k_rec<0><<<256, 512, 0, stream>>>(Gbuf, Whh0f, c * 256, 256, H0e, nullptr,
                                      hstate, cstate, hxw0);
  }
  // layer 1: 2 chunks of 256 steps (inputs = h0 at even t)
  for (int c = 0; c < 2; ++c) {
    k_gemm<256><<<512, 256, 0, stream>>>(H0e, 512, c * 256, Wih1f, bias1, Gbuf);
    k_rec<1><<<256, 512, 0, stream>>>(Gbuf, Whh1f, c * 256, 256, H1q, nullptr,
                                      hstate, cstate, hxw1);
  }
  // layer 2: 1 chunk of 256 steps (inputs = h1 at t%4==0); writes y with 4x broadcast
  k_gemm<256><<<512, 256, 0, stream>>>(H1q, 256, 0, Wih2f, bias2, Gbuf);
  k_rec<2><<<256, 512, 0, stream>>>(Gbuf, Whh2f, 0, 256, nullptr, y,
                                    hstate, cstate, hxw2);
}

// Round 2
// 4500.990 us; speedup vs baseline: 1.0532x; 1.0435x over previous
//
#include <hip/hip_runtime.h>
#include <hip/hip_fp16.h>
#include <stdint.h>
#include <stddef.h>

// DRNN (dilated 3-layer LSTM), B=128, T=1024, F=128, H=256, dil=[1,2,4].
//  - Input GEMMs hoisted out of recurrence (f16 MFMA 16x16x32), G in 67MB chunks.
//  - R5 recurrence rewrite (R4 was W_hh-restream-bound: VGPR_Count=80 < the 128
//    VGPRs the per-thread W rows needed -> 256KB/WG/step from L2 ~= 1.9us/step):
//      * 16 groups x 8 batch, 2 WGs/group (halves of the 128 h-dims), grid 32x512.
//      * Recurrent matvec is now a GEMM per WG: h[8x256] x W_hh^T[256x512] via
//        mfma_f32_16x16x32_f16; W held as B-frags (128 VGPR). Even if spilled,
//        restream cost is amortized 8x across batch.
//      * h in LDS [16][264] (pad 8 -> conflict-free b128 A-frag reads; rows 8-15
//        zeroed for the unused MFMA batch rows). Gates via LDS [4][8][132].
//      * Cell: 2 dims/thread (thread = (batch wv, pair lane)). 2 barriers/step.
//      * Exchange protocol unchanged from verified R3/R4: tagged words
//        {tag=t+1 | f16x2}, parity t&1, relaxed agent atomics, pair same-XCD.

typedef _Float16 f16;
typedef _Float16 v2h __attribute__((ext_vector_type(2)));
typedef _Float16 v8h __attribute__((ext_vector_type(8)));
typedef __fp16 h2_raw __attribute__((ext_vector_type(2)));
typedef __fp16 h8_raw __attribute__((ext_vector_type(8)));
typedef float v4f __attribute__((ext_vector_type(4)));
typedef unsigned long long u64;

#define DEVINL static __device__ __forceinline__

DEVINL float sigm(float x) { return 1.0f / (1.0f + __expf(-x)); }
DEVINL float tanh_(float x) {
  x = fminf(fmaxf(x, -15.0f), 15.0f);
  float e = __expf(-2.0f * x);
  return (1.0f - e) / (1.0f + e);
}
DEVINL v2h pack2(float a, float b) {
  return __builtin_bit_cast(v2h, __builtin_amdgcn_cvt_pkrtz(a, b));
}
DEVINL v4f mfma_16x16x32(v8h a, v8h b, v4f c) {
  return __builtin_amdgcn_mfma_f32_16x16x32_f16(__builtin_bit_cast(h8_raw, a),
                                                __builtin_bit_cast(h8_raw, b), c,
                                                0, 0, 0);
}

// ---------------- prep ----------------

__global__ void k_cvt_x(const float2* __restrict__ src, v2h* __restrict__ dst, int n2) {
  int i = blockIdx.x * blockDim.x + threadIdx.x;
  int st = gridDim.x * blockDim.x;
  for (; i < n2; i += st) {
    float2 v = src[i];
    dst[i] = pack2(v.x, v.y);
  }
}

__global__ void k_prep_w(const float* __restrict__ wih0, const float* __restrict__ whh0,
                         const float* __restrict__ wih1, const float* __restrict__ whh1,
                         const float* __restrict__ wih2, const float* __restrict__ whh2,
                         const float* __restrict__ bi0, const float* __restrict__ bh0,
                         const float* __restrict__ bi1, const float* __restrict__ bh1,
                         const float* __restrict__ bi2, const float* __restrict__ bh2,
                         f16* wih0f, f16* whh0f, f16* wih1f, f16* whh1f,
                         f16* wih2f, f16* whh2f,
                         float* bias0, float* bias1, float* bias2) {
  int i = blockIdx.x * blockDim.x + threadIdx.x;  // grid covers 262144
  if (i < 131072) wih0f[i] = (f16)wih0[i];
  whh0f[i] = (f16)whh0[i];
  wih1f[i] = (f16)wih1[i];
  whh1f[i] = (f16)whh1[i];
  wih2f[i] = (f16)wih2[i];
  whh2f[i] = (f16)whh2[i];
  if (i < 1024) {
    bias0[i] = bi0[i] + bh0[i];
    bias1[i] = bi1[i] + bh1[i];
    bias2[i] = bi2[i] + bh2[i];
  }
}

// ---------------- input GEMM (not a bottleneck; unchanged) ----------------

template <int K>
__launch_bounds__(256)
__global__ void k_gemm(const f16* __restrict__ A, int Tb, int t0,
                       const f16* __restrict__ W, const float* __restrict__ bias,
                       f16* __restrict__ G) {
  constexpr int LDK = K + 8;
  __shared__ f16 As[64 * LDK];
  int b = blockIdx.x >> 2, tb = blockIdx.x & 3;
  const f16* Ablk = A + ((size_t)b * Tb + t0 + tb * 64) * K;
  int tid = threadIdx.x;

  constexpr int NV = 64 * K / 8;
  const uint4* src = (const uint4*)Ablk;
  for (int i = tid; i < NV; i += 256) {
    int e = i * 8;
    int r = e / K, c0 = e % K;
    *(uint4*)&As[r * LDK + c0] = src[i];
  }
  __syncthreads();

  int wave = tid >> 6, lane = tid & 63;
  int lm = lane & 15, lk = (lane >> 4) * 8;

  v8h af[K / 32];
#pragma unroll
  for (int kc = 0; kc < K / 32; ++kc)
    af[kc] = *(const v8h*)&As[(wave * 16 + lm) * LDK + kc * 32 + lk];

  size_t grow0 = (size_t)b * 256 + tb * 64 + wave * 16;
  for (int nt = 0; nt < 64; ++nt) {
    v4f acc = {0.0f, 0.0f, 0.0f, 0.0f};
    const f16* Wrow = W + (size_t)(nt * 16 + lm) * K + lk;
#pragma unroll
    for (int kc = 0; kc < K / 32; ++kc) {
      v8h bf = *(const v8h*)(Wrow + kc * 32);
      acc = mfma_16x16x32(af[kc], bf, acc);
    }
    float bv = bias[nt * 16 + lm];
#pragma unroll
    for (int r = 0; r < 4; ++r) {
      int m = (lane >> 4) * 4 + r;
      G[(grow0 + m) * 1024 + nt * 16 + lm] = (f16)(acc[r] + bv);
    }
  }
}

// ---------------- recurrence (R5: batched MFMA) ----------------
// grid 32 x 512. g=blk&15 (batches [g*8, g*8+8)), half=blk>>4 (dims
// [half*128, half*128+128) of all 4 gates). Pair (blk, blk+16): same XCD.
// Wave wv: gate q=wv&3, colsub=wv>>2 -> 64 cols = 4 N-tiles, K=256 = 8 K-tiles,
// 32 MFMAs/wave/step, W B-frags in VGPRs (loaded once).
// Per step: [A-frags from hbuf, MFMA, gates->gq LDS, G prefetch] BAR1
//           [cell 2 dims/thread, publish, poll partner, hbuf update] BAR2.
// Exchange: hx[(g*2+half)*1024 + (t&1)*512 + bl*64 + p] = {tag=t+1 | f16x2}.

template <int LAYER>
__launch_bounds__(512, 2)
__global__ void k_rec(const f16* __restrict__ G,   // chunk [128][256][1024] f16
                      const f16* __restrict__ Whh, // [1024][256] f16
                      int t0, int steps,
                      f16* __restrict__ Hout, float* __restrict__ y,
                      float* __restrict__ hstate, float* __restrict__ cstate,
                      u64* hxw) {
  int blk = blockIdx.x;
  int g = blk & 15, half = blk >> 4;   // pair (i, i+16) -> same XCD
  int tid = threadIdx.x;
  int lane = tid & 63;
  int wv = tid >> 6;

  // MFMA roles
  int q = wv & 3, cs = wv >> 2;                  // gate, col-subblock
  int colbase = q * 256 + half * 128 + cs * 64;  // + nt*16 + (lane&15)
  int arow = lane & 15;                          // MFMA batch row (0-7 valid)
  int kq = (lane >> 4) * 8;                      // k sub-offset within K-tile

  // cell identity: thread = (batch bl, dim-pair p)
  int bl = wv, p = lane;
  int b = g * 8 + bl;                            // global batch

  __shared__ __align__(16) f16 hbuf[16][264];    // [batch row][k], pad 8
  __shared__ float gq[4][8][132];                // [gate][batch][dim], pad 4

  // W_hh B-fragments: wf[nt*8+kt], lane holds W[col=colbase+nt*16+arow][kt*32+kq+j]
  v8h wf[32];
#pragma unroll
  for (int nt = 0; nt < 4; ++nt)
#pragma unroll
    for (int kt = 0; kt < 8; ++kt)
      wf[nt * 8 + kt] =
          *(const v8h*)&Whh[(size_t)(colbase + nt * 16 + arow) * 256 + kt * 32 + kq];

  // zero hbuf (rows 8-15 stay zero forever -> MFMA rows 8-15 are exact zeros)
  {
    uint32_t* hz = (uint32_t*)&hbuf[0][0];
    for (int i = tid; i < 16 * 264 / 2; i += 512) hz[i] = 0u;
  }
  __syncthreads();

  float c0 = 0.0f, c1 = 0.0f, h0f = 0.0f, h1f = 0.0f;
  if (t0 > 0) {  // restore h (both halves, from global) and own c
    for (int w = tid; w < 1024; w += 512) {
      int rb = w >> 7, kp = w & 127;
      float2 hv = *(const float2*)&hstate[(size_t)(g * 8 + rb) * 256 + 2 * kp];
      *(uint32_t*)&hbuf[rb][2 * kp] = __builtin_bit_cast(uint32_t, pack2(hv.x, hv.y));
    }
    float2 cv = *(const float2*)&cstate[(size_t)b * 256 + half * 128 + 2 * p];
    c0 = cv.x;
    c1 = cv.y;
  }
  __syncthreads();

  u64* myw = hxw + (size_t)(g * 2 + half) * 1024;
  const u64* pw = hxw + (size_t)(g * 2 + (1 - half)) * 1024;

  // G pointer for this cell thread's 4 gate columns
  const f16* Gc = G + (size_t)b * 256 * 1024 + half * 128 + 2 * p;
  uint32_t gv[4], gn[4];
#pragma unroll
  for (int j = 0; j < 4; ++j) gv[j] = *(const uint32_t*)&Gc[j * 256];

  for (int s = 0; s < steps; ++s) {
    int t = t0 + s;
    int par = t & 1;

    // ---- phase 1: MFMA h x W_hh^T ----
    v4f acc[4] = {};
#pragma unroll
    for (int kt = 0; kt < 8; ++kt) {
      v8h a = *(const v8h*)&hbuf[arow][kt * 32 + kq];
#pragma unroll
      for (int nt = 0; nt < 4; ++nt)
        acc[nt] = mfma_16x16x32(a, wf[nt * 8 + kt], acc[nt]);
    }
    // D: batch=(lane>>4)*4+r, dim=cs*64+nt*16+(lane&15). Rows 8-15 dropped.
    if (lane < 32) {
      int r0 = (lane >> 4) * 4;
      int d0 = cs * 64 + (lane & 15);
#pragma unroll
      for (int nt = 0; nt < 4; ++nt)
#pragma unroll
        for (int r = 0; r < 4; ++r)
          gq[q][r0 + r][d0 + nt * 16] = acc[nt][r];
    }
    // prefetch next step's G (used in next phase 2)
    if (s + 1 < steps) {
#pragma unroll
      for (int j = 0; j < 4; ++j)
        gn[j] = *(const uint32_t*)&Gc[(size_t)(s + 1) * 1024 + j * 256];
    }
    __syncthreads();  // BAR1

    // ---- phase 2: cell + exchange ----
    // early poll issue (result checked after cell; hides partner publish RTT)
    const u64* pwp = &pw[(size_t)par * 512 + bl * 64 + p];
    u64 wp = __hip_atomic_load(pwp, __ATOMIC_RELAXED, __HIP_MEMORY_SCOPE_AGENT);

    float2 zi = *(const float2*)&gq[0][bl][2 * p];
    float2 zf = *(const float2*)&gq[1][bl][2 * p];
    float2 zg = *(const float2*)&gq[2][bl][2 * p];
    float2 zo = *(const float2*)&gq[3][bl][2 * p];
    v2h G0 = __builtin_bit_cast(v2h, gv[0]);
    v2h G1 = __builtin_bit_cast(v2h, gv[1]);
    v2h G2 = __builtin_bit_cast(v2h, gv[2]);
    v2h G3 = __builtin_bit_cast(v2h, gv[3]);

    float i0 = sigm(zi.x + (float)G0[0]), i1 = sigm(zi.y + (float)G0[1]);
    float f0 = sigm(zf.x + (float)G1[0]), f1 = sigm(zf.y + (float)G1[1]);
    float g0 = tanh_(zg.x + (float)G2[0]), g1 = tanh_(zg.y + (float)G2[1]);
    float o0 = sigm(zo.x + (float)G3[0]), o1 = sigm(zo.y + (float)G3[1]);
    c0 = f0 * c0 + i0 * g0;
    c1 = f1 * c1 + i1 * g1;
    h0f = o0 * tanh_(c0);
    h1f = o1 * tanh_(c1);

    uint32_t hp = __builtin_bit_cast(uint32_t, pack2(h0f, h1f));
    // publish FIRST (shortest cross-WG path)
    u64 word = ((u64)(uint32_t)(t + 1) << 32) | (u64)hp;
    __hip_atomic_store(&myw[(size_t)par * 512 + bl * 64 + p], word,
                       __ATOMIC_RELAXED, __HIP_MEMORY_SCOPE_AGENT);
    *(uint32_t*)&hbuf[bl][half * 128 + 2 * p] = hp;  // own half for next step

    // outputs (independent of partner; overlap the poll wait)
    if (LAYER == 0) {
      if ((t & 1) == 0) {
        v2h hr; hr[0] = (f16)h0f; hr[1] = (f16)h1f;  // RNE, matches prior Hout
        *(uint32_t*)&Hout[((size_t)b * 512 + (t >> 1)) * 256 + half * 128 + 2 * p] =
            __builtin_bit_cast(uint32_t, hr);
      }
    } else if (LAYER == 1) {
      if ((t & 1) == 0) {
        v2h hr; hr[0] = (f16)h0f; hr[1] = (f16)h1f;
        *(uint32_t*)&Hout[((size_t)b * 256 + (t >> 1)) * 256 + half * 128 + 2 * p] =
            __builtin_bit_cast(uint32_t, hr);
      }
    } else {
      size_t base = ((size_t)b * 1024 + (size_t)t * 4) * 256 + half * 128 + 2 * p;
      float2 hv; hv.x = h0f; hv.y = h1f;
      *(float2*)&y[base] = hv;
      *(float2*)&y[base + 256] = hv;
      *(float2*)&y[base + 512] = hv;
      *(float2*)&y[base + 768] = hv;
    }

    if (s + 1 < steps) {  // partner half of h_t for next step
      while ((int)(wp >> 32) < t + 1)
        wp = __hip_atomic_load(pwp, __ATOMIC_RELAXED, __HIP_MEMORY_SCOPE_AGENT);
      *(uint32_t*)&hbuf[bl][(1 - half) * 128 + 2 * p] = (uint32_t)wp;
    }
    __syncthreads();  // BAR2

#pragma unroll
    for (int j = 0; j < 4; ++j) gv[j] = gn[j];
  }

  // chunk state (own half; partner WG writes its half)
  size_t sb = (size_t)b * 256 + half * 128 + 2 * p;
  float2 hv; hv.x = h0f; hv.y = h1f;
  float2 cv; cv.x = c0; cv.y = c1;
  *(float2*)&hstate[sb] = hv;
  *(float2*)&cstate[sb] = cv;
}

// ---------------- orchestration ----------------

extern "C" void kernel_launch(void* const* d_in, const int* in_sizes, int n_in,
                              void* d_out, int out_size, void* d_ws, size_t ws_size,
                              hipStream_t stream) {
  const float* x = (const float*)d_in[0];
  const float* wih[3] = {(const float*)d_in[1], (const float*)d_in[5], (const float*)d_in[9]};
  const float* whh[3] = {(const float*)d_in[2], (const float*)d_in[6], (const float*)d_in[10]};
  const float* bi[3] = {(const float*)d_in[3], (const float*)d_in[7], (const float*)d_in[11]};
  const float* bh[3] = {(const float*)d_in[4], (const float*)d_in[8], (const float*)d_in[12]};
  float* y = (float*)d_out;

  // workspace layout (~155 MB total)
  char* p = (char*)d_ws;
  f16* Xf = (f16*)p;        p += (size_t)16777216 * 2;        // 33.5 MB
  f16* Wih0f = (f16*)p;     p += (size_t)131072 * 2;
  f16* Whh0f = (f16*)p;     p += (size_t)262144 * 2;
  f16* Wih1f = (f16*)p;     p += (size_t)262144 * 2;
  f16* Whh1f = (f16*)p;     p += (size_t)262144 * 2;
  f16* Wih2f = (f16*)p;     p += (size_t)262144 * 2;
  f16* Whh2f = (f16*)p;     p += (size_t)262144 * 2;
  float* bias0 = (float*)p; p += 4096;
  float* bias1 = (float*)p; p += 4096;
  float* bias2 = (float*)p; p += 4096;
  f16* Gbuf = (f16*)p;      p += (size_t)32768 * 1024 * 2;    // 67 MB chunk
  f16* H0e = (f16*)p;       p += (size_t)128 * 512 * 256 * 2; // 33.5 MB
  f16* H1q = (f16*)p;       p += (size_t)128 * 256 * 256 * 2; // 16.8 MB
  float* hstate = (float*)p; p += (size_t)128 * 256 * 4;
  float* cstate = (float*)p; p += (size_t)128 * 256 * 4;
  u64* hxw0 = (u64*)p;      p += (size_t)16 * 2 * 1024 * 8;   // 256 KB, tagged words
  u64* hxw1 = (u64*)p;      p += (size_t)16 * 2 * 1024 * 8;
  u64* hxw2 = (u64*)p;      p += (size_t)16 * 2 * 1024 * 8;

  // prep
  k_cvt_x<<<4096, 256, 0, stream>>>((const float2*)x, (v2h*)Xf, 8388608);
  k_prep_w<<<1024, 256, 0, stream>>>(wih[0], whh[0], wih[1], whh[1], wih[2], whh[2],
                                     bi[0], bh[0], bi[1], bh[1], bi[2], bh[2],
                                     Wih0f, Whh0f, Wih1f, Whh1f, Wih2f, Whh2f,
                                     bias0, bias1, bias2);

  // layer 0: 4 chunks of 256 steps
  for (int c = 0; c < 4; ++c) {
    k_gemm<128><<<512, 256, 0, stream>>>(Xf, 1024, c * 256, Wih0f, bias0, Gbuf);
    k_rec<0><<<32, 512, 0, stream>>>(Gbuf, Whh0f, c * 256, 256, H0e, nullptr,
                                     hstate, cstate, hxw0);
  }
  // layer 1: 2 chunks of 256 steps (inputs = h0 at even t)
  for (int c = 0; c < 2; ++c) {
    k_gemm<256><<<512, 256, 0, stream>>>(H0e, 512, c * 256, Wih1f, bias1, Gbuf);
    k_rec<1><<<32, 512, 0, stream>>>(Gbuf, Whh1f, c * 256, 256, H1q, nullptr,
                                     hstate, cstate, hxw1);
  }
  // layer 2: 1 chunk of 256 steps (inputs = h1 at t%4==0); writes y with 4x broadcast
  k_gemm<256><<<512, 256, 0, stream>>>(H1q, 256, 0, Wih2f, bias2, Gbuf);
  k_rec<2><<<32, 512, 0, stream>>>(Gbuf, Whh2f, 0, 256, nullptr, y,
                                   hstate, cstate, hxw2);
}